// Round 4
// baseline (1956.839 us; speedup 1.0000x reference)
//
#include <hip/hip_runtime.h>
#include <hip/hip_bf16.h>
#include <stdint.h>

typedef __bf16 bf16x8 __attribute__((ext_vector_type(8)));
typedef float f32x4 __attribute__((ext_vector_type(4)));
typedef unsigned short ushort_t;

static constexpr int kB = 16;
static constexpr int kN = 3137;           // 1 + 56*56
static constexpr long kM = (long)kB * kN; // 50192
static constexpr int kMBLK = (kN + 63) / 64;  // 50 row-blocks per batch

__device__ __forceinline__ float bf2f(ushort_t u) {
  return __uint_as_float(((unsigned)u) << 16);
}
__device__ __forceinline__ ushort_t f2bf(float f) {
  __hip_bfloat16 h = __float2bfloat16(f);
  return *reinterpret_cast<ushort_t*>(&h);
}
// async global->LDS, 16B/lane (used only by the small prep GEMM)
__device__ __forceinline__ void gload16(const void* g, void* l) {
  __builtin_amdgcn_global_load_lds(
      (const __attribute__((address_space(1))) unsigned int*)g,
      (__attribute__((address_space(3))) unsigned int*)(uintptr_t)l,
      16, 0, 0);
}
__device__ __forceinline__ f32x4 mfma16(bf16x8 a, bf16x8 b, f32x4 c) {
  return __builtin_amdgcn_mfma_f32_16x16x32_bf16(a, b, c, 0, 0, 0);
}
// swizzled LDS read of a 16B A-fragment: row*rowB + (kb ^ ((row&7)<<4))
__device__ __forceinline__ bf16x8 ldsA(const ushort_t* base, int row, int rowB, int kb) {
  return *(const bf16x8*)((const char*)base + row * rowB + (kb ^ ((row & 7) << 4)));
}

// ---------------- prep kernels ----------------

__global__ __launch_bounds__(256) void cast_kernel(const float* __restrict__ s,
                                                   ushort_t* __restrict__ d, long n4) {
  long i = (long)blockIdx.x * 256 + threadIdx.x;
  if (i >= n4) return;
  float4 v = *(const float4*)(s + i * 4);
  ushort4 o;
  o.x = f2bf(v.x); o.y = f2bf(v.y); o.z = f2bf(v.z); o.w = f2bf(v.w);
  *(ushort4*)(d + i * 4) = o;
}

// dst[d][e] = bf16(src[e][d]), n x n
__global__ __launch_bounds__(256) void transpose_cast_kernel(const float* __restrict__ src,
                                                             ushort_t* __restrict__ dst,
                                                             int n) {
  __shared__ float tile[32][33];
  const int tx = blockIdx.x * 32, ty = blockIdx.y * 32;
  const int x = threadIdx.x & 31, y0 = threadIdx.x >> 5;
#pragma unroll
  for (int j = 0; j < 32; j += 8)
    tile[y0 + j][x] = src[(long)(ty + y0 + j) * n + tx + x];
  __syncthreads();
#pragma unroll
  for (int j = 0; j < 32; j += 8)
    dst[(long)(tx + y0 + j) * n + ty + x] = f2bf(tile[x][y0 + j]);
}

// c[o] = bf[o] + sum_e wf[o][e]*bp[e]
__global__ __launch_bounds__(256) void cvec_kernel(const float* __restrict__ wf,
                                                   const float* __restrict__ bp,
                                                   const float* __restrict__ bfv,
                                                   float* __restrict__ c) {
  int o = blockIdx.x;
  __shared__ float red[4];
  float s = 0.f;
  for (int e = threadIdx.x; e < 2048; e += 256) s += wf[(long)o * 2048 + e] * bp[e];
#pragma unroll
  for (int off = 32; off >= 1; off >>= 1) s += __shfl_xor(s, off);
  if ((threadIdx.x & 63) == 0) red[threadIdx.x >> 6] = s;
  __syncthreads();
  if (threadIdx.x == 0) c[o] = bfv[o] + red[0] + red[1] + red[2] + red[3];
}

// LayerNorm over 256 dims; 4 rows/block; fp32 in, bf16 out
__global__ __launch_bounds__(256) void ln_kernel(const float* __restrict__ x,
                                                 const float* __restrict__ gw,
                                                 const float* __restrict__ gb,
                                                 ushort_t* __restrict__ out, long M) {
  long row = (long)blockIdx.x * 4 + (threadIdx.x >> 6);
  if (row >= M) return;
  int lane = threadIdx.x & 63;
  float4 v = *(const float4*)(x + row * 256 + lane * 4);
  float s = v.x + v.y + v.z + v.w;
  float s2 = v.x * v.x + v.y * v.y + v.z * v.z + v.w * v.w;
#pragma unroll
  for (int o = 32; o >= 1; o >>= 1) {
    s += __shfl_xor(s, o);
    s2 += __shfl_xor(s2, o);
  }
  float mu = s * (1.f / 256.f);
  float var = fmaxf(s2 * (1.f / 256.f) - mu * mu, 0.f);
  float rs = rsqrtf(var + 1e-5f);
  ushort4 o4;
  o4.x = f2bf((v.x - mu) * rs * gw[lane * 4 + 0] + gb[lane * 4 + 0]);
  o4.y = f2bf((v.y - mu) * rs * gw[lane * 4 + 1] + gb[lane * 4 + 1]);
  o4.z = f2bf((v.z - mu) * rs * gw[lane * 4 + 2] + gb[lane * 4 + 2]);
  o4.w = f2bf((v.w - mu) * rs * gw[lane * 4 + 3] + gb[lane * 4 + 3]);
  *(ushort4*)(out + row * 256 + lane * 4) = o4;
}

// invA[blk] = 1/max(||A_b||, eps)
__global__ __launch_bounds__(256) void anorm_kernel(const float* __restrict__ Av,
                                                    float* __restrict__ invA) {
  int b = blockIdx.x;
  __shared__ float red[4];
  float s = 0.f;
  for (int n = threadIdx.x; n < kN; n += 256) {
    float a = Av[(long)b * kN + n];
    s += a * a;
  }
#pragma unroll
  for (int o = 32; o >= 1; o >>= 1) s += __shfl_xor(s, o);
  if ((threadIdx.x & 63) == 0) red[threadIdx.x >> 6] = s;
  __syncthreads();
  if (threadIdx.x == 0)
    invA[b] = 1.f / fmaxf(sqrtf(red[0] + red[1] + red[2] + red[3]), 1e-12f);
}

// G[b][d] = invA[b] * sum_m Gpart[b][m][d]
__global__ __launch_bounds__(256) void greduce_kernel(const float* __restrict__ Gpart,
                                                      const float* __restrict__ invA,
                                                      float* __restrict__ G) {
  int i = blockIdx.x * 256 + threadIdx.x;  // over 16*2048
  int b = i >> 11, d = i & 2047;
  float s = 0.f;
  for (int m = 0; m < kMBLK; ++m) s += Gpart[((long)b * kMBLK + m) * 2048 + d];
  G[i] = s * invA[b];
}

// ---------------- prep GEMM (wfp = wf @ wp): C = A @ W^T, bf16 out ----------------
__global__ __launch_bounds__(256) void gemm5_kernel(const ushort_t* __restrict__ A,
                                                    const ushort_t* __restrict__ W, int M,
                                                    int K, ushort_t* __restrict__ out0,
                                                    int LDO) {
  __shared__ ushort_t As[128 * 32];
  __shared__ ushort_t Ws[128 * 32];
  const int t = threadIdx.x;
  const int wave = t >> 6;
  const int lane = t & 63;
  const int n0 = blockIdx.x * 128;
  const int m0 = blockIdx.y * 128;
  const int wm = (wave >> 1) * 64;
  const int wn = (wave & 1) * 64;
  f32x4 acc[4][4];
#pragma unroll
  for (int i = 0; i < 4; ++i)
#pragma unroll
    for (int j = 0; j < 4; ++j) acc[i][j] = f32x4{0.f, 0.f, 0.f, 0.f};
  const int r4 = t >> 2;
  const int c8 = (t & 3) * 8;
  long ar0 = m0 + r4;      if (ar0 > M - 1) ar0 = M - 1;
  long ar1 = m0 + 64 + r4; if (ar1 > M - 1) ar1 = M - 1;
  const ushort_t* gA0 = A + ar0 * K + c8;
  const ushort_t* gA1 = A + ar1 * K + c8;
  const ushort_t* gW0 = W + (long)(n0 + r4) * K + c8;
  const ushort_t* gW1 = W + (long)(n0 + 64 + r4) * K + c8;
  char* la = (char*)As + wave * 1024;
  char* lw = (char*)Ws + wave * 1024;
  const int frow = lane & 15;
  const int kg = lane >> 4;
  for (int k0 = 0; k0 < K; k0 += 32) {
    gload16(gA0 + k0, la);
    gload16(gA1 + k0, la + 4096);
    gload16(gW0 + k0, lw);
    gload16(gW1 + k0, lw + 4096);
    __syncthreads();
    bf16x8 af[4], bw[4];
#pragma unroll
    for (int i = 0; i < 4; ++i)
      af[i] = *(const bf16x8*)&As[(wm + i * 16 + frow) * 32 + kg * 8];
#pragma unroll
    for (int i = 0; i < 4; ++i)
      bw[i] = *(const bf16x8*)&Ws[(wn + i * 16 + frow) * 32 + kg * 8];
#pragma unroll
    for (int mi = 0; mi < 4; ++mi)
#pragma unroll
      for (int ni = 0; ni < 4; ++ni) acc[mi][ni] = mfma16(af[mi], bw[ni], acc[mi][ni]);
    __syncthreads();
  }
#pragma unroll
  for (int mi = 0; mi < 4; ++mi)
#pragma unroll
    for (int ni = 0; ni < 4; ++ni) {
      const int gn = n0 + wn + ni * 16 + frow;
#pragma unroll
      for (int j = 0; j < 4; ++j) {
        const int gmi = m0 + wm + mi * 16 + kg * 4 + j;
        if (gmi >= M) continue;
        out0[(long)gmi * LDO + gn] = f2bf(acc[mi][ni][j]);
      }
    }
}

// ---------------- fused block kernels ----------------
// MODE 0 (Q): stats(rs,Av) -> qn -> out = x + qn@wf^T + cvec ; Gpart
// MODE 1 (K): stats(rs) -> kk = kn*G -> out += kk@wfp^T
// MODE 2 (MLP): hdn = gelu(xn2@w1^T+b1) -> out += hdn@w2^T + b2 (cls: += xn2)
// Per block: 64 rows of one batch. 512 threads = 8 waves (2m x 4n).
template <int MODE, int NSUB>
__global__ __launch_bounds__(512) void fused_kernel(
    const ushort_t* __restrict__ xn,   // [kM][256] bf16
    const ushort_t* __restrict__ W1,   // [D1][256] bf16
    const float* __restrict__ bias1,   // [D1]
    const ushort_t* __restrict__ W2,   // [256][D1] bf16
    const float* __restrict__ wg,      // [2048] (MODE0)
    float* __restrict__ Av,            // [kM] out (MODE0)
    float* __restrict__ Gpart,         // [16][kMBLK][2048] out (MODE0)
    const float* __restrict__ G,       // [16][2048] in (MODE1)
    const float* __restrict__ cvec,    // [256] (MODE0)
    const float* __restrict__ xres,    // [kM][256] f32 (MODE0)
    const float* __restrict__ b2v,     // [256] (MODE2)
    float* __restrict__ out)           // [kM][256] f32
{
  constexpr int D1 = NSUB * 128;
  const int mblk = blockIdx.x, b = blockIdx.y;
  const long gr = (long)b * kN + (long)mblk * 64;
  int V = kN - mblk * 64; if (V > 64) V = 64;
  const int t = threadIdx.x, wid = t >> 6, lane = t & 63;
  const int frow = lane & 15, kg = lane >> 4;
  const int wm = (wid >> 2) * 32;
  const int wn1 = (wid & 3) * 32;   // GEMM1 col base (tile width 128)
  const int wn2 = (wid & 3) * 64;   // GEMM2 col base (tile width 256)

  __shared__ ushort_t a_lds[64 * 256];  // xn tile (swizzled)
  __shared__ ushort_t q_lds[64 * 128];  // qn/kk/hdn subtile (swizzled)
  __shared__ float red_s[4][64];
  __shared__ float red_a[4][64];
  __shared__ float rs_lds[64];
  __shared__ float av_lds[64];
  __shared__ float gp_red[2][128];

  // ---- stage xn tile (coalesced, swizzled) ----
#pragma unroll
  for (int it = 0; it < 4; ++it) {
    int c = it * 512 + t;  // 2048 x 16B chunks
    int row = c >> 5, kb = (c & 31) * 16;
    int rr = row < V ? row : V - 1;
    uint4 v = *(const uint4*)(xn + (gr + rr) * 256 + (c & 31) * 8);
    *(uint4*)((char*)a_lds + row * 512 + (kb ^ ((row & 7) << 4))) = v;
  }
  __syncthreads();

  // ---- phase 1: per-row stats (MODE 0/1) ----
  if constexpr (MODE < 2) {
    float srow[2][4] = {{0, 0, 0, 0}, {0, 0, 0, 0}};
    float adot[2][4] = {{0, 0, 0, 0}, {0, 0, 0, 0}};
    for (int ns = 0; ns < NSUB; ++ns) {
      f32x4 acc1[2][2];
#pragma unroll
      for (int mi = 0; mi < 2; ++mi)
#pragma unroll
        for (int ni = 0; ni < 2; ++ni) acc1[mi][ni] = f32x4{0.f, 0.f, 0.f, 0.f};
#pragma unroll
      for (int ks = 0; ks < 8; ++ks) {
        bf16x8 af0 = ldsA(a_lds, wm + frow, 512, ks * 64 + kg * 16);
        bf16x8 af1 = ldsA(a_lds, wm + 16 + frow, 512, ks * 64 + kg * 16);
        bf16x8 bw0 = *(const bf16x8*)(W1 + (long)(ns * 128 + wn1 + frow) * 256 + ks * 32 + kg * 8);
        bf16x8 bw1 = *(const bf16x8*)(W1 + (long)(ns * 128 + wn1 + 16 + frow) * 256 + ks * 32 + kg * 8);
        acc1[0][0] = mfma16(af0, bw0, acc1[0][0]);
        acc1[0][1] = mfma16(af0, bw1, acc1[0][1]);
        acc1[1][0] = mfma16(af1, bw0, acc1[1][0]);
        acc1[1][1] = mfma16(af1, bw1, acc1[1][1]);
      }
      float bb[2], wgv[2];
#pragma unroll
      for (int ni = 0; ni < 2; ++ni) {
        int col = ns * 128 + wn1 + ni * 16 + frow;
        bb[ni] = bias1[col];
        if constexpr (MODE == 0) wgv[ni] = wg[col];
      }
#pragma unroll
      for (int mi = 0; mi < 2; ++mi)
#pragma unroll
        for (int ni = 0; ni < 2; ++ni)
#pragma unroll
          for (int j = 0; j < 4; ++j) {
            float v = acc1[mi][ni][j] + bb[ni];
            srow[mi][j] += v * v;
            if constexpr (MODE == 0) adot[mi][j] += v * wgv[ni];
          }
    }
    // reduce over frow lanes (bits 0-3)
#pragma unroll
    for (int off = 1; off <= 8; off <<= 1)
#pragma unroll
      for (int mi = 0; mi < 2; ++mi)
#pragma unroll
        for (int j = 0; j < 4; ++j) {
          srow[mi][j] += __shfl_xor(srow[mi][j], off);
          if constexpr (MODE == 0) adot[mi][j] += __shfl_xor(adot[mi][j], off);
        }
    if (frow == 0) {
#pragma unroll
      for (int mi = 0; mi < 2; ++mi)
#pragma unroll
        for (int j = 0; j < 4; ++j) {
          int row = wm + mi * 16 + kg * 4 + j;
          red_s[wid & 3][row] = srow[mi][j];
          if constexpr (MODE == 0) red_a[wid & 3][row] = adot[mi][j];
        }
    }
    __syncthreads();
    if (t < 64) {
      float s = red_s[0][t] + red_s[1][t] + red_s[2][t] + red_s[3][t];
      float rs = 1.f / fmaxf(sqrtf(s), 1e-12f);
      rs_lds[t] = rs;
      if constexpr (MODE == 0) {
        float a = (red_a[0][t] + red_a[1][t] + red_a[2][t] + red_a[3][t]) * rs * 0.0625f;
        bool valid = t < V;
        av_lds[t] = valid ? a : 0.f;
        if (valid) Av[gr + t] = a;
      }
    }
    __syncthreads();
  }

  // ---- phase 2: recompute, scale, chain into GEMM2 ----
  f32x4 acc2[2][4];
#pragma unroll
  for (int mi = 0; mi < 2; ++mi)
#pragma unroll
    for (int ni = 0; ni < 4; ++ni) acc2[mi][ni] = f32x4{0.f, 0.f, 0.f, 0.f};

  for (int ns = 0; ns < NSUB; ++ns) {
    f32x4 acc1[2][2];
#pragma unroll
    for (int mi = 0; mi < 2; ++mi)
#pragma unroll
      for (int ni = 0; ni < 2; ++ni) acc1[mi][ni] = f32x4{0.f, 0.f, 0.f, 0.f};
#pragma unroll
    for (int ks = 0; ks < 8; ++ks) {
      bf16x8 af0 = ldsA(a_lds, wm + frow, 512, ks * 64 + kg * 16);
      bf16x8 af1 = ldsA(a_lds, wm + 16 + frow, 512, ks * 64 + kg * 16);
      bf16x8 bw0 = *(const bf16x8*)(W1 + (long)(ns * 128 + wn1 + frow) * 256 + ks * 32 + kg * 8);
      bf16x8 bw1 = *(const bf16x8*)(W1 + (long)(ns * 128 + wn1 + 16 + frow) * 256 + ks * 32 + kg * 8);
      acc1[0][0] = mfma16(af0, bw0, acc1[0][0]);
      acc1[0][1] = mfma16(af0, bw1, acc1[0][1]);
      acc1[1][0] = mfma16(af1, bw0, acc1[1][0]);
      acc1[1][1] = mfma16(af1, bw1, acc1[1][1]);
    }
    float bb[2], sc[2];
#pragma unroll
    for (int ni = 0; ni < 2; ++ni) {
      int col = ns * 128 + wn1 + ni * 16 + frow;
      bb[ni] = bias1[col];
      if constexpr (MODE == 1) sc[ni] = G[b * 2048 + col];
    }
    __syncthreads();  // previous q_lds consumers done
    float gp[2] = {0.f, 0.f};
#pragma unroll
    for (int mi = 0; mi < 2; ++mi)
#pragma unroll
      for (int ni = 0; ni < 2; ++ni)
#pragma unroll
        for (int j = 0; j < 4; ++j) {
          int row = wm + mi * 16 + kg * 4 + j;
          float v = acc1[mi][ni][j] + bb[ni];
          float o;
          if constexpr (MODE == 0) o = v * rs_lds[row];
          else if constexpr (MODE == 1) o = v * rs_lds[row] * sc[ni];
          else o = 0.5f * v * (1.0f + erff(v * 0.70710678118654752f));
          ushort_t us = f2bf(o);
          int cb = (wn1 + ni * 16 + frow) * 2;
          *(ushort_t*)((char*)q_lds + row * 256 + (cb ^ ((row & 7) << 4))) = us;
          if constexpr (MODE == 0) gp[ni] += av_lds[row] * bf2f(us);
        }
    if constexpr (MODE == 0) {
      gp[0] += __shfl_xor(gp[0], 16); gp[0] += __shfl_xor(gp[0], 32);
      gp[1] += __shfl_xor(gp[1], 16); gp[1] += __shfl_xor(gp[1], 32);
      if (kg == 0) {
        gp_red[wm >> 5][wn1 + frow] = gp[0];
        gp_red[wm >> 5][wn1 + 16 + frow] = gp[1];
      }
    }
    __syncthreads();  // q_lds (and gp_red) visible
    if constexpr (MODE == 0) {
      if (t < 128)
        Gpart[((long)b * kMBLK + mblk) * 2048 + ns * 128 + t] = gp_red[0][t] + gp_red[1][t];
    }
#pragma unroll
    for (int ks = 0; ks < 4; ++ks) {
      bf16x8 af0 = ldsA(q_lds, wm + frow, 256, ks * 64 + kg * 16);
      bf16x8 af1 = ldsA(q_lds, wm + 16 + frow, 256, ks * 64 + kg * 16);
#pragma unroll
      for (int ni = 0; ni < 4; ++ni) {
        bf16x8 bw = *(const bf16x8*)(W2 + (long)(wn2 + ni * 16 + frow) * D1 + ns * 128 + ks * 32 + kg * 8);
        acc2[0][ni] = mfma16(af0, bw, acc2[0][ni]);
        acc2[1][ni] = mfma16(af1, bw, acc2[1][ni]);
      }
    }
  }

  // ---- epilogue ----
#pragma unroll
  for (int mi = 0; mi < 2; ++mi)
#pragma unroll
    for (int ni = 0; ni < 4; ++ni)
#pragma unroll
      for (int j = 0; j < 4; ++j) {
        int row = wm + mi * 16 + kg * 4 + j;
        if (row >= V) continue;
        int col = wn2 + ni * 16 + frow;
        long idx = (gr + row) * 256 + col;
        float v = acc2[mi][ni][j];
        if constexpr (MODE == 0) {
          out[idx] = xres[idx] + v + cvec[col];
        } else if constexpr (MODE == 1) {
          out[idx] += v;
        } else {
          int n = mblk * 64 + row;
          if (n == 0) {
            ushort_t u = *(const ushort_t*)((const char*)a_lds + (col * 2));
            out[idx] += bf2f(u);
          } else {
            out[idx] += v + b2v[col];
          }
        }
      }
}

// ---------------- host ----------------

extern "C" void kernel_launch(void* const* d_in, const int* in_sizes, int n_in,
                              void* d_out, int out_size, void* d_ws, size_t ws_size,
                              hipStream_t stream) {
  const float* x = (const float*)d_in[0];
  const float* n1w = (const float*)d_in[1];
  const float* n1b = (const float*)d_in[2];
  const float* wq = (const float*)d_in[3];
  const float* bq = (const float*)d_in[4];
  const float* wk = (const float*)d_in[5];
  const float* bk = (const float*)d_in[6];
  const float* wg = (const float*)d_in[7];
  const float* wp = (const float*)d_in[8];
  const float* bp = (const float*)d_in[9];
  const float* wf = (const float*)d_in[10];
  const float* bfv = (const float*)d_in[11];
  const float* n2w = (const float*)d_in[12];
  const float* n2b = (const float*)d_in[13];
  const float* w1 = (const float*)d_in[14];
  const float* b1 = (const float*)d_in[15];
  const float* w2 = (const float*)d_in[16];
  const float* b2 = (const float*)d_in[17];
  float* out = (float*)d_out;  // also the fp32 attn-residual accumulator

  char* ws = (char*)d_ws;
  size_t off = 0;
  auto alloc = [&](size_t bytes) {
    size_t o = off;
    off += (bytes + 255) & ~(size_t)255;
    return o;
  };
  ushort_t* wq_bf = (ushort_t*)(ws + alloc((size_t)2048 * 256 * 2));
  ushort_t* wk_bf = (ushort_t*)(ws + alloc((size_t)2048 * 256 * 2));
  ushort_t* wf_bf = (ushort_t*)(ws + alloc((size_t)256 * 2048 * 2));
  ushort_t* w1_bf = (ushort_t*)(ws + alloc((size_t)1024 * 256 * 2));
  ushort_t* w2_bf = (ushort_t*)(ws + alloc((size_t)256 * 1024 * 2));
  ushort_t* wpT_bf = (ushort_t*)(ws + alloc((size_t)2048 * 2048 * 2));
  ushort_t* wfp_bf = (ushort_t*)(ws + alloc((size_t)256 * 2048 * 2));
  float* cvec = (float*)(ws + alloc(256 * 4));
  float* Av = (float*)(ws + alloc((size_t)kM * 4));
  float* invA = (float*)(ws + alloc(64));
  float* G = (float*)(ws + alloc((size_t)16 * 2048 * 4));
  float* Gpart = (float*)(ws + alloc((size_t)16 * kMBLK * 2048 * 4));
  ushort_t* xn = (ushort_t*)(ws + alloc((size_t)kM * 256 * 2));
  if (off > ws_size) return;

  // ---- weight prep ----
  cast_kernel<<<512, 256, 0, stream>>>(wq, wq_bf, 2048 * 256 / 4);
  cast_kernel<<<512, 256, 0, stream>>>(wk, wk_bf, 2048 * 256 / 4);
  cast_kernel<<<512, 256, 0, stream>>>(wf, wf_bf, 256 * 2048 / 4);
  cast_kernel<<<256, 256, 0, stream>>>(w1, w1_bf, 1024 * 256 / 4);
  cast_kernel<<<256, 256, 0, stream>>>(w2, w2_bf, 256 * 1024 / 4);
  transpose_cast_kernel<<<dim3(64, 64), 256, 0, stream>>>(wp, wpT_bf, 2048);
  cvec_kernel<<<256, 256, 0, stream>>>(wf, bp, bfv, cvec);
  // wfp = wf @ wp
  gemm5_kernel<<<dim3(16, 2), 256, 0, stream>>>(wf_bf, wpT_bf, 256, 2048, wfp_bf, 2048);

  // ---- LN1 ----
  ln_kernel<<<(int)((kM + 3) / 4), 256, 0, stream>>>(x, n1w, n1b, xn, kM);

  // ---- Q path (fused): stats -> qn -> out = x + qn@wf^T + cvec ; Av, Gpart ----
  fused_kernel<0, 16><<<dim3(kMBLK, 16), 512, 0, stream>>>(
      xn, wq_bf, bq, wf_bf, wg, Av, Gpart, nullptr, cvec, x, nullptr, out);
  anorm_kernel<<<16, 256, 0, stream>>>(Av, invA);
  greduce_kernel<<<128, 256, 0, stream>>>(Gpart, invA, G);

  // ---- K path (fused): stats -> kk -> out += kk@wfp^T ----
  fused_kernel<1, 16><<<dim3(kMBLK, 16), 512, 0, stream>>>(
      xn, wk_bf, bk, wfp_bf, nullptr, nullptr, nullptr, G, nullptr, nullptr, nullptr, out);

  // ---- LN2 ----
  ln_kernel<<<(int)((kM + 3) / 4), 256, 0, stream>>>(out, n2w, n2b, xn, kM);

  // ---- MLP (fused): hdn = gelu(xn2@w1^T+b1); out += hdn@w2^T + b2 (cls: += xn2) ----
  fused_kernel<2, 8><<<dim3(kMBLK, 16), 512, 0, stream>>>(
      xn, w1_bf, b1, w2_bf, nullptr, nullptr, nullptr, nullptr, nullptr, nullptr, b2, out);
}

// Round 5
// 816.244 us; speedup vs baseline: 2.3974x; 2.3974x over previous
//
#include <hip/hip_runtime.h>
#include <hip/hip_bf16.h>
#include <stdint.h>

typedef __bf16 bf16x8 __attribute__((ext_vector_type(8)));
typedef float f32x4 __attribute__((ext_vector_type(4)));
typedef unsigned short ushort_t;

static constexpr int kB = 16;
static constexpr int kN = 3137;           // 1 + 56*56
static constexpr long kM = (long)kB * kN; // 50192
static constexpr int kNS = 64;            // tvec n-split

__device__ __forceinline__ float bf2f(ushort_t u) {
  return __uint_as_float(((unsigned)u) << 16);
}
__device__ __forceinline__ ushort_t f2bf(float f) {
  __hip_bfloat16 h = __float2bfloat16(f);
  return *reinterpret_cast<ushort_t*>(&h);
}
__device__ __forceinline__ void gload16(const void* g, void* l) {
  __builtin_amdgcn_global_load_lds(
      (const __attribute__((address_space(1))) unsigned int*)g,
      (__attribute__((address_space(3))) unsigned int*)(uintptr_t)l,
      16, 0, 0);
}
__device__ __forceinline__ f32x4 mfma16(bf16x8 a, bf16x8 b, f32x4 c) {
  return __builtin_amdgcn_mfma_f32_16x16x32_bf16(a, b, c, 0, 0, 0);
}

// ---------------- prep kernels ----------------

__global__ __launch_bounds__(256) void cast_kernel(const float* __restrict__ s,
                                                   ushort_t* __restrict__ d, long n4) {
  long i = (long)blockIdx.x * 256 + threadIdx.x;
  if (i >= n4) return;
  float4 v = *(const float4*)(s + i * 4);
  ushort4 o;
  o.x = f2bf(v.x); o.y = f2bf(v.y); o.z = f2bf(v.z); o.w = f2bf(v.w);
  *(ushort4*)(d + i * 4) = o;
}

// dst[c][r] = bf16(src[r][c]); src R x C (both multiples of 32)
__global__ __launch_bounds__(256) void transpose_cast_kernel(const float* __restrict__ src,
                                                             ushort_t* __restrict__ dst,
                                                             int R, int C) {
  __shared__ float tile[32][33];
  const int tx = blockIdx.x * 32, ty = blockIdx.y * 32;  // tx: col base, ty: row base
  const int x = threadIdx.x & 31, y0 = threadIdx.x >> 5;
#pragma unroll
  for (int j = 0; j < 32; j += 8)
    tile[y0 + j][x] = src[(long)(ty + y0 + j) * C + tx + x];
  __syncthreads();
#pragma unroll
  for (int j = 0; j < 32; j += 8)
    dst[(long)(tx + y0 + j) * R + ty + x] = f2bf(tile[x][y0 + j]);
}

// out[i] = (add?add[i]:0) + sum_k A[i*K+k]*v[k]; 4 rows/block (1 wave each)
__global__ __launch_bounds__(256) void gemv_kernel(const ushort_t* __restrict__ A,
                                                   const float* __restrict__ v,
                                                   const float* __restrict__ add,
                                                   float* __restrict__ out, int rows,
                                                   int K) {
  int row = blockIdx.x * 4 + (threadIdx.x >> 6);
  if (row >= rows) return;
  int lane = threadIdx.x & 63;
  float acc = 0.f;
  for (int k0 = lane * 8; k0 < K; k0 += 512) {
    uint4 raw = *(const uint4*)(A + (long)row * K + k0);
    const ushort_t* u = (const ushort_t*)&raw;
#pragma unroll
    for (int j = 0; j < 8; ++j) acc += bf2f(u[j]) * v[k0 + j];
  }
#pragma unroll
  for (int o = 32; o >= 1; o >>= 1) acc += __shfl_xor(acc, o);
  if (lane == 0) out[row] = (add ? add[row] : 0.f) + acc;
}

// scal = { ||bq||^2, ||bk||^2, bq.wg }
__global__ __launch_bounds__(256) void scalars_kernel(const float* __restrict__ bq,
                                                      const float* __restrict__ bk,
                                                      const float* __restrict__ wg,
                                                      float* __restrict__ scal) {
  __shared__ float red[3][4];
  float s0 = 0, s1 = 0, s2 = 0;
  for (int i = threadIdx.x; i < 2048; i += 256) {
    s0 += bq[i] * bq[i];
    s1 += bk[i] * bk[i];
    s2 += bq[i] * wg[i];
  }
#pragma unroll
  for (int o = 32; o >= 1; o >>= 1) {
    s0 += __shfl_xor(s0, o); s1 += __shfl_xor(s1, o); s2 += __shfl_xor(s2, o);
  }
  int w = threadIdx.x >> 6;
  if ((threadIdx.x & 63) == 0) { red[0][w] = s0; red[1][w] = s1; red[2][w] = s2; }
  __syncthreads();
  if (threadIdx.x < 3)
    scal[threadIdx.x] = red[threadIdx.x][0] + red[threadIdx.x][1] +
                        red[threadIdx.x][2] + red[threadIdx.x][3];
}

// LayerNorm over 256; 4 rows/block; optionally per-row dots with uq/uk/vg
__global__ __launch_bounds__(256) void ln_kernel(
    const float* __restrict__ x, const float* __restrict__ gw,
    const float* __restrict__ gb, ushort_t* __restrict__ out, long M,
    const float* __restrict__ uqv, const float* __restrict__ ukv,
    const float* __restrict__ vgv, float* __restrict__ duq,
    float* __restrict__ duk, float* __restrict__ dvg) {
  long row = (long)blockIdx.x * 4 + (threadIdx.x >> 6);
  if (row >= M) return;
  int lane = threadIdx.x & 63;
  float4 v = *(const float4*)(x + row * 256 + lane * 4);
  float s = v.x + v.y + v.z + v.w;
  float s2 = v.x * v.x + v.y * v.y + v.z * v.z + v.w * v.w;
#pragma unroll
  for (int o = 32; o >= 1; o >>= 1) {
    s += __shfl_xor(s, o);
    s2 += __shfl_xor(s2, o);
  }
  float mu = s * (1.f / 256.f);
  float var = fmaxf(s2 * (1.f / 256.f) - mu * mu, 0.f);
  float rsd = rsqrtf(var + 1e-5f);
  float e[4];
  ushort4 o4;
  e[0] = bf2f(o4.x = f2bf((v.x - mu) * rsd * gw[lane * 4 + 0] + gb[lane * 4 + 0]));
  e[1] = bf2f(o4.y = f2bf((v.y - mu) * rsd * gw[lane * 4 + 1] + gb[lane * 4 + 1]));
  e[2] = bf2f(o4.z = f2bf((v.z - mu) * rsd * gw[lane * 4 + 2] + gb[lane * 4 + 2]));
  e[3] = bf2f(o4.w = f2bf((v.w - mu) * rsd * gw[lane * 4 + 3] + gb[lane * 4 + 3]));
  *(ushort4*)(out + row * 256 + lane * 4) = o4;
  if (duq) {
    int base = lane * 4;
    float a = e[0] * uqv[base] + e[1] * uqv[base + 1] + e[2] * uqv[base + 2] + e[3] * uqv[base + 3];
    float b = e[0] * ukv[base] + e[1] * ukv[base + 1] + e[2] * ukv[base + 2] + e[3] * ukv[base + 3];
    float c = e[0] * vgv[base] + e[1] * vgv[base + 1] + e[2] * vgv[base + 2] + e[3] * vgv[base + 3];
#pragma unroll
    for (int o = 32; o >= 1; o >>= 1) {
      a += __shfl_xor(a, o); b += __shfl_xor(b, o); c += __shfl_xor(c, o);
    }
    if (lane == 0) { duq[row] = a; duk[row] = b; dvg[row] = c; }
  }
}

// per-row: rs_q, rs_k, Av from partials + dots + scalars
__global__ __launch_bounds__(256) void reduce_rows_kernel(
    const float* __restrict__ part, const float* __restrict__ duq,
    const float* __restrict__ duk, const float* __restrict__ dvg,
    const float* __restrict__ scal, float* __restrict__ rs_q,
    float* __restrict__ rs_k, float* __restrict__ Av) {
  long i = (long)blockIdx.x * 256 + threadIdx.x;
  if (i >= kM) return;
  float sq = part[i] + part[kM + i] + part[2 * kM + i] + part[3 * kM + i] +
             2.f * duq[i] + scal[0];
  float sk = part[4 * kM + i] + part[5 * kM + i] + part[6 * kM + i] +
             part[7 * kM + i] + 2.f * duk[i] + scal[1];
  float rq = 1.f / fmaxf(sqrtf(fmaxf(sq, 0.f)), 1e-12f);
  float rk = 1.f / fmaxf(sqrtf(fmaxf(sk, 0.f)), 1e-12f);
  rs_q[i] = rq;
  rs_k[i] = rk;
  Av[i] = rq * (dvg[i] + scal[2]) * 0.0625f;
}

// invA[b] = 1/max(||A_b||, eps)
__global__ __launch_bounds__(256) void anorm_kernel(const float* __restrict__ Av,
                                                    float* __restrict__ invA) {
  int b = blockIdx.x;
  __shared__ float red[4];
  float s = 0.f;
  for (int n = threadIdx.x; n < kN; n += 256) {
    float a = Av[(long)b * kN + n];
    s += a * a;
  }
#pragma unroll
  for (int o = 32; o >= 1; o >>= 1) s += __shfl_xor(s, o);
  if ((threadIdx.x & 63) == 0) red[threadIdx.x >> 6] = s;
  __syncthreads();
  if (threadIdx.x == 0)
    invA[b] = 1.f / fmaxf(sqrtf(red[0] + red[1] + red[2] + red[3]), 1e-12f);
}

// tpart[(ns*16+b)][e] = sum_{n in slice} c[n]*xn[b,n,e];  c = invA*Av*rs_q
__global__ __launch_bounds__(256) void tvec_kernel(const ushort_t* __restrict__ xn,
                                                   const float* __restrict__ Av,
                                                   const float* __restrict__ rs_q,
                                                   const float* __restrict__ invA,
                                                   float* __restrict__ tpart,
                                                   float* __restrict__ Spart) {
  const int ns = blockIdx.x, b = blockIdx.y;
  const int n0 = ns * 50;
  int cnt = kN - n0; if (cnt > 50) cnt = 50; if (cnt < 0) cnt = 0;
  __shared__ float c_lds[50];
  const int t = threadIdx.x;
  if (t < cnt) {
    long gi = (long)b * kN + n0 + t;
    c_lds[t] = invA[b] * Av[gi] * rs_q[gi];
  }
  __syncthreads();
  float acc = 0.f;
  const ushort_t* p = xn + ((long)b * kN + n0) * 256 + t;
  for (int i = 0; i < cnt; ++i, p += 256) acc += c_lds[i] * bf2f(*p);
  tpart[((long)ns * 16 + b) * 256 + t] = acc;
  if (t == 0) {
    float s = 0.f;
    for (int i = 0; i < cnt; ++i) s += c_lds[i];
    Spart[ns * 16 + b] = s;
  }
}

// t[b][e] = sum_ns tpart ; S[b] = sum_ns Spart
__global__ __launch_bounds__(256) void treduce_kernel(const float* __restrict__ tpart,
                                                      const float* __restrict__ Spart,
                                                      float* __restrict__ tb,
                                                      float* __restrict__ S) {
  int b = blockIdx.x, e = threadIdx.x;
  float s = 0.f;
  for (int ns = 0; ns < kNS; ++ns) s += tpart[((long)ns * 16 + b) * 256 + e];
  tb[b * 256 + e] = s;
  if (e == 0) {
    float ss = 0.f;
    for (int ns = 0; ns < kNS; ++ns) ss += Spart[ns * 16 + b];
    S[b] = ss;
  }
}

// G[b*2048+d] = wq[d,:] . t[b] + bq[d]*S[b]   (wave per output)
__global__ __launch_bounds__(256) void gvec_kernel(const float* __restrict__ wq,
                                                   const float* __restrict__ bq,
                                                   const float* __restrict__ tb,
                                                   const float* __restrict__ S,
                                                   float* __restrict__ G) {
  int i = blockIdx.x * 4 + (threadIdx.x >> 6);  // over 16*2048
  int b = i >> 11, d = i & 2047;
  int lane = threadIdx.x & 63;
  float4 w4 = *(const float4*)(wq + (long)d * 256 + lane * 4);
  const float* tv = tb + b * 256 + lane * 4;
  float acc = w4.x * tv[0] + w4.y * tv[1] + w4.z * tv[2] + w4.w * tv[3];
#pragma unroll
  for (int o = 32; o >= 1; o >>= 1) acc += __shfl_xor(acc, o);
  if (lane == 0) G[i] = acc + bq[d] * S[b];
}

// wfpG[b][o][d] = wfp[o][d] * G[b][d]
__global__ __launch_bounds__(256) void wfpg_kernel(const ushort_t* __restrict__ wfp,
                                                   const float* __restrict__ G,
                                                   ushort_t* __restrict__ wfpG) {
  long i = ((long)blockIdx.x * 256 + threadIdx.x) * 8;
  int b = (int)(i >> 19);
  long rem = i & 524287;
  int d = (int)(rem & 2047);
  uint4 raw = *(const uint4*)(wfp + rem);
  ushort_t* u = (ushort_t*)&raw;
  const float* g = G + b * 2048 + d;
#pragma unroll
  for (int j = 0; j < 8; ++j) u[j] = f2bf(bf2f(u[j]) * g[j]);
  *(uint4*)(wfpG + (long)b * 524288 + rem) = raw;
}

// ---------------- GEMM: C = A @ W^T (+epilogues), swizzled LDS ----------------
// EPI 5: bf16 store (+b1?) | 3: gelu bf16 | 4: f32 RMW + cls passthrough
// EPI 7: out = auxf + rs[row]*(v+b1) + b2 | 8: out += rs[row]*(v+b2)
// EPI 10: stats partials (no C store)
template <int EPI, int LDO>
__global__ __launch_bounds__(256) void gemm_kernel(
    const ushort_t* __restrict__ A, const ushort_t* __restrict__ W, int M, int K,
    const float* __restrict__ b1, const float* __restrict__ b2,
    const float* __restrict__ rs, const float* __restrict__ auxf,
    const ushort_t* __restrict__ auxb, void* __restrict__ out0,
    float* __restrict__ partbuf, long zA, long zW, long zRow, int zB2) {
  __shared__ ushort_t As[128 * 32];
  __shared__ ushort_t Ws[128 * 32];
  const int z = blockIdx.z;
  A += (long)z * zA;
  W += (long)z * zW;
  if (b2) b2 += (long)z * zB2;
  const int t = threadIdx.x;
  const int wave = t >> 6;
  const int lane = t & 63;
  const int n0 = blockIdx.x * 128;
  const int m0 = blockIdx.y * 128;
  const int wm = (wave >> 1) * 64;
  const int wn = (wave & 1) * 64;

  f32x4 acc[4][4];
#pragma unroll
  for (int i = 0; i < 4; ++i)
#pragma unroll
    for (int j = 0; j < 4; ++j) acc[i][j] = f32x4{0.f, 0.f, 0.f, 0.f};

  const int r4 = t >> 2;
  // pre-swizzled source k-offset so linear LDS dest == swizzled layout
  const int c8s = (((t & 3) ^ ((r4 >> 1) & 3)) * 8);
  long ar0 = m0 + r4;      if (ar0 > M - 1) ar0 = M - 1;
  long ar1 = m0 + 64 + r4; if (ar1 > M - 1) ar1 = M - 1;
  const ushort_t* gA0 = A + ar0 * K + c8s;
  const ushort_t* gA1 = A + ar1 * K + c8s;
  const ushort_t* gW0 = W + (long)(n0 + r4) * K + c8s;
  const ushort_t* gW1 = W + (long)(n0 + 64 + r4) * K + c8s;
  char* la = (char*)As + wave * 1024;
  char* lw = (char*)Ws + wave * 1024;

  const int frow = lane & 15;
  const int kg = lane >> 4;
  const int ksw = ((kg ^ ((frow >> 1) & 3)) * 8);  // swizzled read slot

  for (int k0 = 0; k0 < K; k0 += 32) {
    gload16(gA0 + k0, la);
    gload16(gA1 + k0, la + 4096);
    gload16(gW0 + k0, lw);
    gload16(gW1 + k0, lw + 4096);
    __syncthreads();
    bf16x8 af[4], bw[4];
#pragma unroll
    for (int i = 0; i < 4; ++i)
      af[i] = *(const bf16x8*)&As[(wm + i * 16 + frow) * 32 + ksw];
#pragma unroll
    for (int i = 0; i < 4; ++i)
      bw[i] = *(const bf16x8*)&Ws[(wn + i * 16 + frow) * 32 + ksw];
#pragma unroll
    for (int mi = 0; mi < 4; ++mi)
#pragma unroll
      for (int ni = 0; ni < 4; ++ni) acc[mi][ni] = mfma16(af[mi], bw[ni], acc[mi][ni]);
    __syncthreads();
  }

  if constexpr (EPI == 10) {
#pragma unroll
    for (int mi = 0; mi < 4; ++mi) {
#pragma unroll
      for (int j = 0; j < 4; ++j) {
        const int gmi = m0 + wm + mi * 16 + kg * 4 + j;
        float rp = 0.f;
        if (gmi < M) {
#pragma unroll
          for (int ni = 0; ni < 4; ++ni) {
            const int gn = n0 + wn + ni * 16 + frow;
            rp += acc[mi][ni][j] * bf2f(A[(long)gmi * K + (gn & 255)]);
          }
        }
#pragma unroll
        for (int off = 1; off <= 8; off <<= 1) rp += __shfl_xor(rp, off);
        if (frow == 0 && gmi < M)
          partbuf[(long)(blockIdx.x * 2 + (wave & 1)) * M + gmi] = rp;
      }
    }
    return;
  }

#pragma unroll
  for (int mi = 0; mi < 4; ++mi)
#pragma unroll
    for (int ni = 0; ni < 4; ++ni) {
      const int gn = n0 + wn + ni * 16 + frow;
#pragma unroll
      for (int j = 0; j < 4; ++j) {
        const int gmi = m0 + wm + mi * 16 + kg * 4 + j;
        if (gmi >= M) continue;
        const long grow = (long)z * zRow + gmi;
        const long idx = grow * LDO + gn;
        float v = acc[mi][ni][j];
        if constexpr (EPI == 5) {
          if (b1) v += b1[gn];
          ((ushort_t*)out0)[idx] = f2bf(v);
        } else if constexpr (EPI == 3) {
          v += b1[gn];
          ((ushort_t*)out0)[idx] = f2bf(0.5f * v * (1.0f + erff(v * 0.70710678118654752f)));
        } else if constexpr (EPI == 4) {
          v += b1[gn];
          const bool cls = (grow % kN) == 0;
          ((float*)out0)[idx] += cls ? bf2f(auxb[idx]) : v;
        } else if constexpr (EPI == 7) {
          ((float*)out0)[idx] = auxf[idx] + rs[grow] * (v + b1[gn]) + b2[gn];
        } else if constexpr (EPI == 8) {
          ((float*)out0)[idx] += rs[grow] * (v + b2[gn]);
        }
      }
    }
}

// ---------------- host ----------------

extern "C" void kernel_launch(void* const* d_in, const int* in_sizes, int n_in,
                              void* d_out, int out_size, void* d_ws, size_t ws_size,
                              hipStream_t stream) {
  const float* x = (const float*)d_in[0];
  const float* n1w = (const float*)d_in[1];
  const float* n1b = (const float*)d_in[2];
  const float* wq = (const float*)d_in[3];
  const float* bq = (const float*)d_in[4];
  const float* wk = (const float*)d_in[5];
  const float* bk = (const float*)d_in[6];
  const float* wg = (const float*)d_in[7];
  const float* wp = (const float*)d_in[8];
  const float* bp = (const float*)d_in[9];
  const float* wf = (const float*)d_in[10];
  const float* bfv = (const float*)d_in[11];
  const float* n2w = (const float*)d_in[12];
  const float* n2b = (const float*)d_in[13];
  const float* w1 = (const float*)d_in[14];
  const float* b1 = (const float*)d_in[15];
  const float* w2 = (const float*)d_in[16];
  const float* b2 = (const float*)d_in[17];
  float* out = (float*)d_out;  // fp32 residual accumulator and final output

  char* ws = (char*)d_ws;
  size_t off = 0;
  auto alloc = [&](size_t bytes) {
    size_t o = off;
    off += (bytes + 255) & ~(size_t)255;
    return o;
  };
  ushort_t* wqT = (ushort_t*)(ws + alloc((size_t)256 * 2048 * 2));
  ushort_t* wkT = (ushort_t*)(ws + alloc((size_t)256 * 2048 * 2));
  ushort_t* wpT = (ushort_t*)(ws + alloc((size_t)2048 * 2048 * 2));
  ushort_t* wf_bf = (ushort_t*)(ws + alloc((size_t)256 * 2048 * 2));
  ushort_t* w1_bf = (ushort_t*)(ws + alloc((size_t)1024 * 256 * 2));
  ushort_t* w2_bf = (ushort_t*)(ws + alloc((size_t)256 * 1024 * 2));
  ushort_t* MqMk = (ushort_t*)(ws + alloc((size_t)512 * 256 * 2));
  ushort_t* wfq_bf = (ushort_t*)(ws + alloc((size_t)256 * 256 * 2));
  ushort_t* wfp_bf = (ushort_t*)(ws + alloc((size_t)256 * 2048 * 2));
  ushort_t* wfpG = (ushort_t*)(ws + alloc((size_t)16 * 256 * 2048 * 2));
  ushort_t* Wc = (ushort_t*)(ws + alloc((size_t)16 * 256 * 256 * 2));
  float* uq = (float*)(ws + alloc(256 * 4));
  float* uk = (float*)(ws + alloc(256 * 4));
  float* vg = (float*)(ws + alloc(256 * 4));
  float* cfq = (float*)(ws + alloc(256 * 4));
  float* cvec = (float*)(ws + alloc(256 * 4));
  float* cb = (float*)(ws + alloc((size_t)16 * 256 * 4));
  float* scal = (float*)(ws + alloc(256));
  ushort_t* xn = (ushort_t*)(ws + alloc((size_t)kM * 256 * 2));
  float* duq = (float*)(ws + alloc((size_t)kM * 4));
  float* duk = (float*)(ws + alloc((size_t)kM * 4));
  float* dvg = (float*)(ws + alloc((size_t)kM * 4));
  float* part = (float*)(ws + alloc((size_t)8 * kM * 4));
  float* rs_q = (float*)(ws + alloc((size_t)kM * 4));
  float* rs_k = (float*)(ws + alloc((size_t)kM * 4));
  float* Av = (float*)(ws + alloc((size_t)kM * 4));
  float* invA = (float*)(ws + alloc(64));
  float* tpart = (float*)(ws + alloc((size_t)kNS * 16 * 256 * 4));
  float* Spart = (float*)(ws + alloc((size_t)kNS * 16 * 4));
  float* tb = (float*)(ws + alloc((size_t)16 * 256 * 4));
  float* Sb = (float*)(ws + alloc(64));
  float* G = (float*)(ws + alloc((size_t)16 * 2048 * 4));
  ushort_t* hdn = (ushort_t*)(ws + alloc((size_t)kM * 1024 * 2));
  if (off > ws_size) return;

  // ---- weight prep ----
  transpose_cast_kernel<<<dim3(8, 64), 256, 0, stream>>>(wq, wqT, 2048, 256);
  transpose_cast_kernel<<<dim3(8, 64), 256, 0, stream>>>(wk, wkT, 2048, 256);
  transpose_cast_kernel<<<dim3(64, 64), 256, 0, stream>>>(wp, wpT, 2048, 2048);
  cast_kernel<<<512, 256, 0, stream>>>(wf, wf_bf, 256 * 2048 / 4);
  cast_kernel<<<256, 256, 0, stream>>>(w1, w1_bf, 1024 * 256 / 4);
  cast_kernel<<<256, 256, 0, stream>>>(w2, w2_bf, 256 * 1024 / 4);
  // Mq = wqT@wqT^T(K) ; Mk ; wfq = wf@wq ; wfp = wf@wp
  gemm_kernel<5, 256><<<dim3(2, 2), 256, 0, stream>>>(
      wqT, wqT, 256, 2048, nullptr, nullptr, nullptr, nullptr, nullptr, MqMk,
      nullptr, 0, 0, 0, 0);
  gemm_kernel<5, 256><<<dim3(2, 2), 256, 0, stream>>>(
      wkT, wkT, 256, 2048, nullptr, nullptr, nullptr, nullptr, nullptr, MqMk + 65536,
      nullptr, 0, 0, 0, 0);
  gemm_kernel<5, 256><<<dim3(2, 2), 256, 0, stream>>>(
      wf_bf, wqT, 256, 2048, nullptr, nullptr, nullptr, nullptr, nullptr, wfq_bf,
      nullptr, 0, 0, 0, 0);
  gemm_kernel<5, 2048><<<dim3(16, 2), 256, 0, stream>>>(
      wf_bf, wpT, 256, 2048, nullptr, nullptr, nullptr, nullptr, nullptr, wfp_bf,
      nullptr, 0, 0, 0, 0);
  gemv_kernel<<<64, 256, 0, stream>>>(wqT, bq, nullptr, uq, 256, 2048);
  gemv_kernel<<<64, 256, 0, stream>>>(wkT, bk, nullptr, uk, 256, 2048);
  gemv_kernel<<<64, 256, 0, stream>>>(wqT, wg, nullptr, vg, 256, 2048);
  gemv_kernel<<<64, 256, 0, stream>>>(wf_bf, bq, nullptr, cfq, 256, 2048);
  gemv_kernel<<<64, 256, 0, stream>>>(wf_bf, bp, bfv, cvec, 256, 2048);
  scalars_kernel<<<1, 256, 0, stream>>>(bq, bk, wg, scal);

  const int mt = (int)((kM + 127) / 128);  // 393

  // ---- LN1 (+dots) ----
  ln_kernel<<<(int)((kM + 3) / 4), 256, 0, stream>>>(x, n1w, n1b, xn, kM, uq, uk, vg,
                                                     duq, duk, dvg);
  // ---- stats GEMM: partials of xn^T Mq xn and xn^T Mk xn ----
  gemm_kernel<10, 256><<<dim3(4, mt), 256, 0, stream>>>(
      xn, MqMk, (int)kM, 256, nullptr, nullptr, nullptr, nullptr, nullptr, nullptr,
      part, 0, 0, 0, 0);
  reduce_rows_kernel<<<(int)((kM + 255) / 256), 256, 0, stream>>>(
      part, duq, duk, dvg, scal, rs_q, rs_k, Av);
  anorm_kernel<<<16, 256, 0, stream>>>(Av, invA);

  // ---- consumer Q: out = x + rs_q*(xn@wfq^T + cfq) + cvec ----
  gemm_kernel<7, 256><<<dim3(2, mt), 256, 0, stream>>>(
      xn, wfq_bf, (int)kM, 256, cfq, cvec, rs_q, x, nullptr, out, nullptr, 0, 0, 0, 0);

  // ---- G = wq @ t + bq*S ----
  tvec_kernel<<<dim3(kNS, 16), 256, 0, stream>>>(xn, Av, rs_q, invA, tpart, Spart);
  treduce_kernel<<<16, 256, 0, stream>>>(tpart, Spart, tb, Sb);
  gvec_kernel<<<16 * 2048 / 4, 256, 0, stream>>>(wq, bq, tb, Sb, G);

  // ---- Wc[b] = (wfp . G[b]) @ wk ; cb[b] = (wfp . G[b]) @ bk ----
  wfpg_kernel<<<4096, 256, 0, stream>>>(wfp_bf, G, wfpG);
  gemv_kernel<<<1024, 256, 0, stream>>>(wfpG, bk, nullptr, cb, 16 * 256, 2048);
  gemm_kernel<5, 256><<<dim3(2, 2, 16), 256, 0, stream>>>(
      wfpG, wkT, 256, 2048, nullptr, nullptr, nullptr, nullptr, nullptr, Wc,
      nullptr, 524288, 0, 256, 0);

  // ---- consumer K: out += rs_k*(xn@Wc[b]^T + cb[b]) ----
  gemm_kernel<8, 256><<<dim3(2, 25, 16), 256, 0, stream>>>(
      xn, Wc, kN, 256, nullptr, cb, rs_k, nullptr, nullptr, out, nullptr,
      (long)kN * 256, 65536, kN, 256);

  // ---- LN2 ----
  ln_kernel<<<(int)((kM + 3) / 4), 256, 0, stream>>>(out, n2w, n2b, xn, kM, nullptr,
                                                     nullptr, nullptr, nullptr,
                                                     nullptr, nullptr);
  // ---- MLP ----
  gemm_kernel<3, 1024><<<dim3(8, mt), 256, 0, stream>>>(
      xn, w1_bf, (int)kM, 256, b1, nullptr, nullptr, nullptr, nullptr, hdn,
      nullptr, 0, 0, 0, 0);
  gemm_kernel<4, 256><<<dim3(2, mt), 256, 0, stream>>>(
      hdn, w2_bf, (int)kM, 1024, b2, nullptr, nullptr, nullptr, xn, out,
      nullptr, 0, 0, 0, 0);
}

// Round 6
// 455.592 us; speedup vs baseline: 4.2952x; 1.7916x over previous
//
#include <hip/hip_runtime.h>
#include <hip/hip_bf16.h>
#include <stdint.h>

typedef __bf16 bf16x8 __attribute__((ext_vector_type(8)));
typedef float f32x4 __attribute__((ext_vector_type(4)));
typedef unsigned short ushort_t;

static constexpr int kB = 16;
static constexpr int kN = 3137;           // 1 + 56*56
static constexpr long kM = (long)kB * kN; // 50192
static constexpr int kNS = 64;            // tvec n-split

__device__ __forceinline__ float bf2f(ushort_t u) {
  return __uint_as_float(((unsigned)u) << 16);
}
__device__ __forceinline__ ushort_t f2bf(float f) {
  __hip_bfloat16 h = __float2bfloat16(f);
  return *reinterpret_cast<ushort_t*>(&h);
}
__device__ __forceinline__ void gload16(const void* g, void* l) {
  __builtin_amdgcn_global_load_lds(
      (const __attribute__((address_space(1))) unsigned int*)g,
      (__attribute__((address_space(3))) unsigned int*)(uintptr_t)l,
      16, 0, 0);
}
__device__ __forceinline__ f32x4 mfma16(bf16x8 a, bf16x8 b, f32x4 c) {
  return __builtin_amdgcn_mfma_f32_16x16x32_bf16(a, b, c, 0, 0, 0);
}

// ---------------- prep kernels (unchanged from round 5) ----------------

__global__ __launch_bounds__(256) void cast_kernel(const float* __restrict__ s,
                                                   ushort_t* __restrict__ d, long n4) {
  long i = (long)blockIdx.x * 256 + threadIdx.x;
  if (i >= n4) return;
  float4 v = *(const float4*)(s + i * 4);
  ushort4 o;
  o.x = f2bf(v.x); o.y = f2bf(v.y); o.z = f2bf(v.z); o.w = f2bf(v.w);
  *(ushort4*)(d + i * 4) = o;
}

__global__ __launch_bounds__(256) void transpose_cast_kernel(const float* __restrict__ src,
                                                             ushort_t* __restrict__ dst,
                                                             int R, int C) {
  __shared__ float tile[32][33];
  const int tx = blockIdx.x * 32, ty = blockIdx.y * 32;
  const int x = threadIdx.x & 31, y0 = threadIdx.x >> 5;
#pragma unroll
  for (int j = 0; j < 32; j += 8)
    tile[y0 + j][x] = src[(long)(ty + y0 + j) * C + tx + x];
  __syncthreads();
#pragma unroll
  for (int j = 0; j < 32; j += 8)
    dst[(long)(tx + y0 + j) * R + ty + x] = f2bf(tile[x][y0 + j]);
}

__global__ __launch_bounds__(256) void gemv_kernel(const ushort_t* __restrict__ A,
                                                   const float* __restrict__ v,
                                                   const float* __restrict__ add,
                                                   float* __restrict__ out, int rows,
                                                   int K) {
  int row = blockIdx.x * 4 + (threadIdx.x >> 6);
  if (row >= rows) return;
  int lane = threadIdx.x & 63;
  float acc = 0.f;
  for (int k0 = lane * 8; k0 < K; k0 += 512) {
    uint4 raw = *(const uint4*)(A + (long)row * K + k0);
    const ushort_t* u = (const ushort_t*)&raw;
#pragma unroll
    for (int j = 0; j < 8; ++j) acc += bf2f(u[j]) * v[k0 + j];
  }
#pragma unroll
  for (int o = 32; o >= 1; o >>= 1) acc += __shfl_xor(acc, o);
  if (lane == 0) out[row] = (add ? add[row] : 0.f) + acc;
}

__global__ __launch_bounds__(256) void scalars_kernel(const float* __restrict__ bq,
                                                      const float* __restrict__ bk,
                                                      const float* __restrict__ wg,
                                                      float* __restrict__ scal) {
  __shared__ float red[3][4];
  float s0 = 0, s1 = 0, s2 = 0;
  for (int i = threadIdx.x; i < 2048; i += 256) {
    s0 += bq[i] * bq[i];
    s1 += bk[i] * bk[i];
    s2 += bq[i] * wg[i];
  }
#pragma unroll
  for (int o = 32; o >= 1; o >>= 1) {
    s0 += __shfl_xor(s0, o); s1 += __shfl_xor(s1, o); s2 += __shfl_xor(s2, o);
  }
  int w = threadIdx.x >> 6;
  if ((threadIdx.x & 63) == 0) { red[0][w] = s0; red[1][w] = s1; red[2][w] = s2; }
  __syncthreads();
  if (threadIdx.x < 3)
    scal[threadIdx.x] = red[threadIdx.x][0] + red[threadIdx.x][1] +
                        red[threadIdx.x][2] + red[threadIdx.x][3];
}

__global__ __launch_bounds__(256) void ln_kernel(
    const float* __restrict__ x, const float* __restrict__ gw,
    const float* __restrict__ gb, ushort_t* __restrict__ out, long M,
    const float* __restrict__ uqv, const float* __restrict__ ukv,
    const float* __restrict__ vgv, float* __restrict__ duq,
    float* __restrict__ duk, float* __restrict__ dvg) {
  long row = (long)blockIdx.x * 4 + (threadIdx.x >> 6);
  if (row >= M) return;
  int lane = threadIdx.x & 63;
  float4 v = *(const float4*)(x + row * 256 + lane * 4);
  float s = v.x + v.y + v.z + v.w;
  float s2 = v.x * v.x + v.y * v.y + v.z * v.z + v.w * v.w;
#pragma unroll
  for (int o = 32; o >= 1; o >>= 1) {
    s += __shfl_xor(s, o);
    s2 += __shfl_xor(s2, o);
  }
  float mu = s * (1.f / 256.f);
  float var = fmaxf(s2 * (1.f / 256.f) - mu * mu, 0.f);
  float rsd = rsqrtf(var + 1e-5f);
  float e[4];
  ushort4 o4;
  e[0] = bf2f(o4.x = f2bf((v.x - mu) * rsd * gw[lane * 4 + 0] + gb[lane * 4 + 0]));
  e[1] = bf2f(o4.y = f2bf((v.y - mu) * rsd * gw[lane * 4 + 1] + gb[lane * 4 + 1]));
  e[2] = bf2f(o4.z = f2bf((v.z - mu) * rsd * gw[lane * 4 + 2] + gb[lane * 4 + 2]));
  e[3] = bf2f(o4.w = f2bf((v.w - mu) * rsd * gw[lane * 4 + 3] + gb[lane * 4 + 3]));
  *(ushort4*)(out + row * 256 + lane * 4) = o4;
  if (duq) {
    int base = lane * 4;
    float a = e[0] * uqv[base] + e[1] * uqv[base + 1] + e[2] * uqv[base + 2] + e[3] * uqv[base + 3];
    float b = e[0] * ukv[base] + e[1] * ukv[base + 1] + e[2] * ukv[base + 2] + e[3] * ukv[base + 3];
    float c = e[0] * vgv[base] + e[1] * vgv[base + 1] + e[2] * vgv[base + 2] + e[3] * vgv[base + 3];
#pragma unroll
    for (int o = 32; o >= 1; o >>= 1) {
      a += __shfl_xor(a, o); b += __shfl_xor(b, o); c += __shfl_xor(c, o);
    }
    if (lane == 0) { duq[row] = a; duk[row] = b; dvg[row] = c; }
  }
}

// per-row: rs_q, rs_k, Av from 16 partial slices + dots + scalars
__global__ __launch_bounds__(256) void reduce_rows_kernel(
    const float* __restrict__ part, const float* __restrict__ duq,
    const float* __restrict__ duk, const float* __restrict__ dvg,
    const float* __restrict__ scal, float* __restrict__ rs_q,
    float* __restrict__ rs_k, float* __restrict__ Av) {
  long i = (long)blockIdx.x * 256 + threadIdx.x;
  if (i >= kM) return;
  float sq = 0.f, sk = 0.f;
#pragma unroll
  for (int s = 0; s < 8; ++s) sq += part[(long)s * kM + i];
#pragma unroll
  for (int s = 8; s < 16; ++s) sk += part[(long)s * kM + i];
  sq += 2.f * duq[i] + scal[0];
  sk += 2.f * duk[i] + scal[1];
  float rq = 1.f / fmaxf(sqrtf(fmaxf(sq, 0.f)), 1e-12f);
  float rk = 1.f / fmaxf(sqrtf(fmaxf(sk, 0.f)), 1e-12f);
  rs_q[i] = rq;
  rs_k[i] = rk;
  Av[i] = rq * (dvg[i] + scal[2]) * 0.0625f;
}

__global__ __launch_bounds__(256) void anorm_kernel(const float* __restrict__ Av,
                                                    float* __restrict__ invA) {
  int b = blockIdx.x;
  __shared__ float red[4];
  float s = 0.f;
  for (int n = threadIdx.x; n < kN; n += 256) {
    float a = Av[(long)b * kN + n];
    s += a * a;
  }
#pragma unroll
  for (int o = 32; o >= 1; o >>= 1) s += __shfl_xor(s, o);
  if ((threadIdx.x & 63) == 0) red[threadIdx.x >> 6] = s;
  __syncthreads();
  if (threadIdx.x == 0)
    invA[b] = 1.f / fmaxf(sqrtf(red[0] + red[1] + red[2] + red[3]), 1e-12f);
}

__global__ __launch_bounds__(256) void tvec_kernel(const ushort_t* __restrict__ xn,
                                                   const float* __restrict__ Av,
                                                   const float* __restrict__ rs_q,
                                                   const float* __restrict__ invA,
                                                   float* __restrict__ tpart,
                                                   float* __restrict__ Spart) {
  const int ns = blockIdx.x, b = blockIdx.y;
  const int n0 = ns * 50;
  int cnt = kN - n0; if (cnt > 50) cnt = 50; if (cnt < 0) cnt = 0;
  __shared__ float c_lds[50];
  const int t = threadIdx.x;
  if (t < cnt) {
    long gi = (long)b * kN + n0 + t;
    c_lds[t] = invA[b] * Av[gi] * rs_q[gi];
  }
  __syncthreads();
  float acc = 0.f;
  const ushort_t* p = xn + ((long)b * kN + n0) * 256 + t;
  for (int i = 0; i < cnt; ++i, p += 256) acc += c_lds[i] * bf2f(*p);
  tpart[((long)ns * 16 + b) * 256 + t] = acc;
  if (t == 0) {
    float s = 0.f;
    for (int i = 0; i < cnt; ++i) s += c_lds[i];
    Spart[ns * 16 + b] = s;
  }
}

__global__ __launch_bounds__(256) void treduce_kernel(const float* __restrict__ tpart,
                                                      const float* __restrict__ Spart,
                                                      float* __restrict__ tb,
                                                      float* __restrict__ S) {
  int b = blockIdx.x, e = threadIdx.x;
  float s = 0.f;
  for (int ns = 0; ns < kNS; ++ns) s += tpart[((long)ns * 16 + b) * 256 + e];
  tb[b * 256 + e] = s;
  if (e == 0) {
    float ss = 0.f;
    for (int ns = 0; ns < kNS; ++ns) ss += Spart[ns * 16 + b];
    S[b] = ss;
  }
}

__global__ __launch_bounds__(256) void gvec_kernel(const float* __restrict__ wq,
                                                   const float* __restrict__ bq,
                                                   const float* __restrict__ tb,
                                                   const float* __restrict__ S,
                                                   float* __restrict__ G) {
  int i = blockIdx.x * 4 + (threadIdx.x >> 6);
  int b = i >> 11, d = i & 2047;
  int lane = threadIdx.x & 63;
  float4 w4 = *(const float4*)(wq + (long)d * 256 + lane * 4);
  const float* tv = tb + b * 256 + lane * 4;
  float acc = w4.x * tv[0] + w4.y * tv[1] + w4.z * tv[2] + w4.w * tv[3];
#pragma unroll
  for (int o = 32; o >= 1; o >>= 1) acc += __shfl_xor(acc, o);
  if (lane == 0) G[i] = acc + bq[d] * S[b];
}

__global__ __launch_bounds__(256) void wfpg_kernel(const ushort_t* __restrict__ wfp,
                                                   const float* __restrict__ G,
                                                   ushort_t* __restrict__ wfpG) {
  long i = ((long)blockIdx.x * 256 + threadIdx.x) * 8;
  int b = (int)(i >> 19);
  long rem = i & 524287;
  int d = (int)(rem & 2047);
  uint4 raw = *(const uint4*)(wfp + rem);
  ushort_t* u = (ushort_t*)&raw;
  const float* g = G + b * 2048 + d;
#pragma unroll
  for (int j = 0; j < 8; ++j) u[j] = f2bf(bf2f(u[j]) * g[j]);
  *(uint4*)(wfpG + (long)b * 524288 + rem) = raw;
}

// ---------------- GEMM v2: 512 threads, dbuf 2-phase, XCD-banded ----------------
// C = A @ W^T over tiles 128x128; waves 2m x 4n (64x32 wave tiles); BK=32.
// EPI 5: bf16 store (+b1?), LDS-coalesced
// EPI 3: bf16 gelu(v+b1), LDS-coalesced
// EPI 4: f32 RMW: out += (row%kN==0 ? bf2f(auxb) : v+b1)
// EPI 9: DUAL: out = auxf + rs1*(vq+b1) + b3 + rs2*(vk+b2[z])
// EPI 10: stats partials (16 slices)
template <int EPI, int LDO>
__global__ __launch_bounds__(512) void gemm_kernel(
    const ushort_t* __restrict__ A, const ushort_t* __restrict__ W,
    const ushort_t* __restrict__ W2, int M, int K, int NT, int MT,
    const float* __restrict__ b1, const float* __restrict__ b2,
    const float* __restrict__ b3, const float* __restrict__ rs1,
    const float* __restrict__ rs2, const float* __restrict__ auxf,
    const ushort_t* __restrict__ auxb, void* __restrict__ out0,
    float* __restrict__ partbuf, long zA, long zW2, long zRow, int zB2) {
  constexpr bool DUAL = (EPI == 9);
  constexpr int BUFB = DUAL ? 24576 : 16384;
  __shared__ char smem[2 * BUFB];

  const int t = threadIdx.x;
  const int wid = t >> 6, lane = t & 63;
  const int frow = lane & 15, kg = lane >> 4;
  const int wm = (wid >> 2) * 64;
  const int wn = (wid & 3) * 32;

  // XCD-banded bijective decode: same-m n-tiles land on the same XCD
  const int total = (int)gridDim.x;
  const int qq = total >> 3, rr = total & 7;
  const int xb = blockIdx.x & 7, ib = blockIdx.x >> 3;
  const int lg = (xb < rr ? xb * (qq + 1) : rr * (qq + 1) + (xb - rr) * qq) + ib;
  const int nt = lg % NT;
  const int mt = (lg / NT) % MT;
  const int z = lg / (NT * MT);
  const int n0 = nt * 128, m0 = mt * 128;

  A += (long)z * zA;
  const ushort_t* W2z = nullptr;
  if constexpr (DUAL) W2z = W2 + (long)z * zW2;

  // per-lane global source addrs (pre-swizzled col so linear LDS == swizzled)
  const int srow = t >> 2;
  const int csw = ((t & 3) ^ ((t >> 3) & 3)) * 8;
  long arow = m0 + srow; if (arow > M - 1) arow = M - 1;
  const ushort_t* gA = A + arow * K + csw;
  const ushort_t* gW = W + (long)(n0 + srow) * K + csw;
  const ushort_t* gW2 = nullptr;
  if constexpr (DUAL) gW2 = W2z + (long)(n0 + srow) * K + csw;

  f32x4 acc[4][2];
  f32x4 accd[4][2];
#pragma unroll
  for (int mi = 0; mi < 4; ++mi)
#pragma unroll
    for (int ni = 0; ni < 2; ++ni) {
      acc[mi][ni] = f32x4{0.f, 0.f, 0.f, 0.f};
      if constexpr (DUAL) accd[mi][ni] = f32x4{0.f, 0.f, 0.f, 0.f};
    }

  const int KT = K >> 5;
  auto stage = [&](int bi, int k0) {
    char* base = smem + bi * BUFB + (wid << 10);  // wave-uniform
    gload16(gA + k0, base);
    gload16(gW + k0, base + 8192);
    if constexpr (DUAL) gload16(gW2 + k0, base + 16384);
  };

  stage(0, 0);
  __syncthreads();
  for (int kt = 0; kt < KT; ++kt) {
    const int cur = kt & 1;
    if (kt + 1 < KT) stage(cur ^ 1, (kt + 1) << 5);  // prefetch next (in flight)
    const char* bA = smem + cur * BUFB;
    bf16x8 af[4], bw[2], bw2[2];
#pragma unroll
    for (int mi = 0; mi < 4; ++mi) {
      int r = wm + mi * 16 + frow;
      af[mi] = *(const bf16x8*)(bA + r * 64 + ((kg ^ ((r >> 1) & 3)) << 4));
    }
#pragma unroll
    for (int ni = 0; ni < 2; ++ni) {
      int r = wn + ni * 16 + frow;
      int sw = (kg ^ ((r >> 1) & 3)) << 4;
      bw[ni] = *(const bf16x8*)(bA + 8192 + r * 64 + sw);
      if constexpr (DUAL) bw2[ni] = *(const bf16x8*)(bA + 16384 + r * 64 + sw);
    }
#pragma unroll
    for (int mi = 0; mi < 4; ++mi)
#pragma unroll
      for (int ni = 0; ni < 2; ++ni) {
        acc[mi][ni] = mfma16(af[mi], bw[ni], acc[mi][ni]);
        if constexpr (DUAL) accd[mi][ni] = mfma16(af[mi], bw2[ni], accd[mi][ni]);
      }
    __syncthreads();  // drains vmcnt -> next buffer ready; orders buffer reuse
  }

  if constexpr (EPI == 10) {
    // partials of row-quadratic forms: dot acc-row with xn-row (L2-hot)
#pragma unroll
    for (int mi = 0; mi < 4; ++mi)
#pragma unroll
      for (int j = 0; j < 4; ++j) {
        const int gmi = m0 + wm + mi * 16 + kg * 4 + j;
        float rp = 0.f;
        if (gmi < M) {
#pragma unroll
          for (int ni = 0; ni < 2; ++ni) {
            const int gn = n0 + wn + ni * 16 + frow;
            rp += acc[mi][ni][j] * bf2f(A[(long)gmi * K + (gn & 255)]);
          }
        }
#pragma unroll
        for (int off = 1; off <= 8; off <<= 1) rp += __shfl_xor(rp, off);
        if (frow == 0 && gmi < M)
          partbuf[(long)(nt * 4 + (wid & 3)) * M + gmi] = rp;
      }
    return;
  }

  if constexpr (EPI == 3 || EPI == 5) {
    // coalesced bf16 store via LDS (reuses staging buffers)
#pragma unroll
    for (int mi = 0; mi < 4; ++mi)
#pragma unroll
      for (int ni = 0; ni < 2; ++ni) {
        const int gn = n0 + wn + ni * 16 + frow;
        const int lcolb = (wn + ni * 16 + frow) * 2;
#pragma unroll
        for (int j = 0; j < 4; ++j) {
          const int lrow = wm + mi * 16 + kg * 4 + j;
          float v = acc[mi][ni][j];
          if (b1) v += b1[gn];
          if constexpr (EPI == 3)
            v = 0.5f * v * (1.0f + erff(v * 0.70710678118654752f));
          *(ushort_t*)(smem + lrow * 256 + (lcolb ^ ((lrow & 7) << 4))) = f2bf(v);
        }
      }
    __syncthreads();
#pragma unroll
    for (int p = 0; p < 4; ++p) {
      const int r = p * 32 + (t >> 4);
      const int cb = (t & 15) * 16;
      uint4 v = *(const uint4*)(smem + r * 256 + (cb ^ ((r & 7) << 4)));
      const int gmi = m0 + r;
      if (gmi < M)
        *(uint4*)((ushort_t*)out0 + ((long)z * zRow + gmi) * LDO + n0 + cb / 2) = v;
    }
    return;
  }

#pragma unroll
  for (int mi = 0; mi < 4; ++mi)
#pragma unroll
    for (int ni = 0; ni < 2; ++ni) {
      const int gn = n0 + wn + ni * 16 + frow;
#pragma unroll
      for (int j = 0; j < 4; ++j) {
        const int gmi = m0 + wm + mi * 16 + kg * 4 + j;
        if (gmi >= M) continue;
        const long grow = (long)z * zRow + gmi;
        const long idx = grow * LDO + gn;
        if constexpr (EPI == 4) {
          float v = acc[mi][ni][j] + b1[gn];
          const bool cls = (gmi % kN) == 0;
          ((float*)out0)[idx] += cls ? bf2f(auxb[idx]) : v;
        } else {  // EPI == 9 (DUAL consumer)
          float v = auxf[idx] + rs1[grow] * (acc[mi][ni][j] + b1[gn]) + b3[gn] +
                    rs2[grow] * (accd[mi][ni][j] + b2[z * zB2 + gn]);
          ((float*)out0)[idx] = v;
        }
      }
    }
}

// ---------------- host ----------------

extern "C" void kernel_launch(void* const* d_in, const int* in_sizes, int n_in,
                              void* d_out, int out_size, void* d_ws, size_t ws_size,
                              hipStream_t stream) {
  const float* x = (const float*)d_in[0];
  const float* n1w = (const float*)d_in[1];
  const float* n1b = (const float*)d_in[2];
  const float* wq = (const float*)d_in[3];
  const float* bq = (const float*)d_in[4];
  const float* wk = (const float*)d_in[5];
  const float* bk = (const float*)d_in[6];
  const float* wg = (const float*)d_in[7];
  const float* wp = (const float*)d_in[8];
  const float* bp = (const float*)d_in[9];
  const float* wf = (const float*)d_in[10];
  const float* bfv = (const float*)d_in[11];
  const float* n2w = (const float*)d_in[12];
  const float* n2b = (const float*)d_in[13];
  const float* w1 = (const float*)d_in[14];
  const float* b1 = (const float*)d_in[15];
  const float* w2 = (const float*)d_in[16];
  const float* b2 = (const float*)d_in[17];
  float* out = (float*)d_out;

  char* ws = (char*)d_ws;
  size_t off = 0;
  auto alloc = [&](size_t bytes) {
    size_t o = off;
    off += (bytes + 255) & ~(size_t)255;
    return o;
  };
  ushort_t* wqT = (ushort_t*)(ws + alloc((size_t)256 * 2048 * 2));
  ushort_t* wkT = (ushort_t*)(ws + alloc((size_t)256 * 2048 * 2));
  ushort_t* wpT = (ushort_t*)(ws + alloc((size_t)2048 * 2048 * 2));
  ushort_t* wf_bf = (ushort_t*)(ws + alloc((size_t)256 * 2048 * 2));
  ushort_t* w1_bf = (ushort_t*)(ws + alloc((size_t)1024 * 256 * 2));
  ushort_t* w2_bf = (ushort_t*)(ws + alloc((size_t)256 * 1024 * 2));
  ushort_t* MqMk = (ushort_t*)(ws + alloc((size_t)512 * 256 * 2));
  ushort_t* wfq_bf = (ushort_t*)(ws + alloc((size_t)256 * 256 * 2));
  ushort_t* wfp_bf = (ushort_t*)(ws + alloc((size_t)256 * 2048 * 2));
  ushort_t* wfpG = (ushort_t*)(ws + alloc((size_t)16 * 256 * 2048 * 2));
  ushort_t* Wc = (ushort_t*)(ws + alloc((size_t)16 * 256 * 256 * 2));
  float* uq = (float*)(ws + alloc(256 * 4));
  float* uk = (float*)(ws + alloc(256 * 4));
  float* vg = (float*)(ws + alloc(256 * 4));
  float* cfq = (float*)(ws + alloc(256 * 4));
  float* cvec = (float*)(ws + alloc(256 * 4));
  float* cb = (float*)(ws + alloc((size_t)16 * 256 * 4));
  float* scal = (float*)(ws + alloc(256));
  ushort_t* xn = (ushort_t*)(ws + alloc((size_t)kM * 256 * 2));
  float* duq = (float*)(ws + alloc((size_t)kM * 4));
  float* duk = (float*)(ws + alloc((size_t)kM * 4));
  float* dvg = (float*)(ws + alloc((size_t)kM * 4));
  float* part = (float*)(ws + alloc((size_t)16 * kM * 4));
  float* rs_q = (float*)(ws + alloc((size_t)kM * 4));
  float* rs_k = (float*)(ws + alloc((size_t)kM * 4));
  float* Av = (float*)(ws + alloc((size_t)kM * 4));
  float* invA = (float*)(ws + alloc(64));
  float* tpart = (float*)(ws + alloc((size_t)kNS * 16 * 256 * 4));
  float* Spart = (float*)(ws + alloc((size_t)kNS * 16 * 4));
  float* tb = (float*)(ws + alloc((size_t)16 * 256 * 4));
  float* Sb = (float*)(ws + alloc(64));
  float* G = (float*)(ws + alloc((size_t)16 * 2048 * 4));
  ushort_t* hdn = (ushort_t*)(ws + alloc((size_t)kM * 1024 * 2));
  if (off > ws_size) return;

  // ---- weight prep ----
  transpose_cast_kernel<<<dim3(8, 64), 256, 0, stream>>>(wq, wqT, 2048, 256);
  transpose_cast_kernel<<<dim3(8, 64), 256, 0, stream>>>(wk, wkT, 2048, 256);
  transpose_cast_kernel<<<dim3(64, 64), 256, 0, stream>>>(wp, wpT, 2048, 2048);
  cast_kernel<<<512, 256, 0, stream>>>(wf, wf_bf, 256 * 2048 / 4);
  cast_kernel<<<256, 256, 0, stream>>>(w1, w1_bf, 1024 * 256 / 4);
  cast_kernel<<<256, 256, 0, stream>>>(w2, w2_bf, 256 * 1024 / 4);
  gemv_kernel<<<64, 256, 0, stream>>>(wqT, bq, nullptr, uq, 256, 2048);
  gemv_kernel<<<64, 256, 0, stream>>>(wkT, bk, nullptr, uk, 256, 2048);
  gemv_kernel<<<64, 256, 0, stream>>>(wqT, wg, nullptr, vg, 256, 2048);
  gemv_kernel<<<64, 256, 0, stream>>>(wf_bf, bq, nullptr, cfq, 256, 2048);
  gemv_kernel<<<64, 256, 0, stream>>>(wf_bf, bp, bfv, cvec, 256, 2048);
  scalars_kernel<<<1, 256, 0, stream>>>(bq, bk, wg, scal);
  // Mq, Mk, wfq, wfp
  gemm_kernel<5, 256><<<4, 512, 0, stream>>>(
      wqT, wqT, nullptr, 256, 2048, 2, 2, nullptr, nullptr, nullptr, nullptr,
      nullptr, nullptr, nullptr, MqMk, nullptr, 0, 0, 0, 0);
  gemm_kernel<5, 256><<<4, 512, 0, stream>>>(
      wkT, wkT, nullptr, 256, 2048, 2, 2, nullptr, nullptr, nullptr, nullptr,
      nullptr, nullptr, nullptr, MqMk + 65536, nullptr, 0, 0, 0, 0);
  gemm_kernel<5, 256><<<4, 512, 0, stream>>>(
      wf_bf, wqT, nullptr, 256, 2048, 2, 2, nullptr, nullptr, nullptr, nullptr,
      nullptr, nullptr, nullptr, wfq_bf, nullptr, 0, 0, 0, 0);
  gemm_kernel<5, 2048><<<32, 512, 0, stream>>>(
      wf_bf, wpT, nullptr, 256, 2048, 16, 2, nullptr, nullptr, nullptr, nullptr,
      nullptr, nullptr, nullptr, wfp_bf, nullptr, 0, 0, 0, 0);

  // ---- LN1 (+dots) ----
  ln_kernel<<<(int)((kM + 3) / 4), 256, 0, stream>>>(x, n1w, n1b, xn, kM, uq, uk, vg,
                                                     duq, duk, dvg);
  // ---- stats GEMM ----
  gemm_kernel<10, 256><<<1572, 512, 0, stream>>>(
      xn, MqMk, nullptr, (int)kM, 256, 4, 393, nullptr, nullptr, nullptr, nullptr,
      nullptr, nullptr, nullptr, nullptr, part, 0, 0, 0, 0);
  reduce_rows_kernel<<<(int)((kM + 255) / 256), 256, 0, stream>>>(
      part, duq, duk, dvg, scal, rs_q, rs_k, Av);
  anorm_kernel<<<16, 256, 0, stream>>>(Av, invA);

  // ---- G = wq @ t + bq*S ----
  tvec_kernel<<<dim3(kNS, 16), 256, 0, stream>>>(xn, Av, rs_q, invA, tpart, Spart);
  treduce_kernel<<<16, 256, 0, stream>>>(tpart, Spart, tb, Sb);
  gvec_kernel<<<16 * 2048 / 4, 256, 0, stream>>>(wq, bq, tb, Sb, G);

  // ---- Wc[b] = (wfp . G[b]) @ wk ; cb[b] = (wfp . G[b]) @ bk ----
  wfpg_kernel<<<4096, 256, 0, stream>>>(wfp_bf, G, wfpG);
  gemv_kernel<<<1024, 256, 0, stream>>>(wfpG, bk, nullptr, cb, 16 * 256, 2048);
  gemm_kernel<5, 256><<<64, 512, 0, stream>>>(
      wfpG, wkT, nullptr, 256, 2048, 2, 2, nullptr, nullptr, nullptr, nullptr,
      nullptr, nullptr, nullptr, Wc, nullptr, 524288, 0, 256, 0);

  // ---- fused consumer Q+K (dual acc):
  //      out = x + rs_q*(xn@wfq^T+cfq) + cvec + rs_k*(xn@Wc[b]^T+cb[b]) ----
  gemm_kernel<9, 256><<<800, 512, 0, stream>>>(
      xn, wfq_bf, Wc, kN, 256, 2, 25, cfq, cb, cvec, rs_q, rs_k, x, nullptr, out,
      nullptr, (long)kN * 256, 65536, kN, 256);

  // ---- LN2 ----
  ln_kernel<<<(int)((kM + 3) / 4), 256, 0, stream>>>(out, n2w, n2b, xn, kM, nullptr,
                                                     nullptr, nullptr, nullptr,
                                                     nullptr, nullptr);
  // ---- MLP ----
  gemm_kernel<3, 1024><<<3144, 512, 0, stream>>>(
      xn, w1_bf, nullptr, (int)kM, 256, 8, 393, b1, nullptr, nullptr, nullptr,
      nullptr, nullptr, nullptr, hdn, nullptr, 0, 0, 0, 0);
  gemm_kernel<4, 256><<<786, 512, 0, stream>>>(
      hdn, w2_bf, nullptr, (int)kM, 1024, 2, 393, b2, nullptr, nullptr, nullptr,
      nullptr, nullptr, xn, out, nullptr, 0, 0, 0, 0);
}